// Round 3
// baseline (485.284 us; speedup 1.0000x reference)
//
#include <hip/hip_runtime.h>
#include <hip/hip_bf16.h>
#include <cstdint>
#include <cstddef>

#define AS1 __attribute__((address_space(1)))
#define AS3 __attribute__((address_space(3)))

typedef __bf16 bf16x8 __attribute__((ext_vector_type(8)));
typedef float  floatx4 __attribute__((ext_vector_type(4)));

__device__ __forceinline__ void load_lds16(const void* g, void* l) {
    // async global->LDS, 16B/lane; LDS dest is wave-uniform base + lane*16
    __builtin_amdgcn_global_load_lds((AS1 void*)g, (AS3 void*)l, 16, 0, 0);
}

__device__ __forceinline__ float fexp2(float x) { return __builtin_amdgcn_exp2f(x); }
__device__ __forceinline__ float flog2(float x) { return __builtin_amdgcn_logf(x); }

// ---------------------------------------------------------------------------
// Fused prep: all masks + fp32->bf16 in ONE launch (5 launches -> 1).
// Region layout in blocks of 256 elements:
//   [0,4096)      x    -> xb   (copy),              cols=128
//   [4096,5120)   W0   -> w0m  keep=(r%127 >= c),   cols=128
//   [5120,21504)  W1   -> w1m  keep=(r%127>=c%127), cols=2048
//   [21504,37888) W2   -> w2m  keep=(r%127>=c%127), cols=2048
//   [37888,70656) W3   -> w3m  keep=((r>>5)>c%127), cols=2048
// ---------------------------------------------------------------------------
__global__ __launch_bounds__(256)
void prep_all(const float* __restrict__ x,  const float* __restrict__ W0,
              const float* __restrict__ W1, const float* __restrict__ W2,
              const float* __restrict__ W3,
              __bf16* __restrict__ xb,  __bf16* __restrict__ w0m,
              __bf16* __restrict__ w1m, __bf16* __restrict__ w2m,
              __bf16* __restrict__ w3m)
{
    const int blk = blockIdx.x;
    const float* src; __bf16* dst; int shift, mode; long base;
    if (blk < 4096)        { src = x;  dst = xb;  shift = 7;  mode = 3; base = 0; }
    else if (blk < 5120)   { src = W0; dst = w0m; shift = 7;  mode = 0; base = 4096L * 256; }
    else if (blk < 21504)  { src = W1; dst = w1m; shift = 11; mode = 1; base = 5120L * 256; }
    else if (blk < 37888)  { src = W2; dst = w2m; shift = 11; mode = 1; base = 21504L * 256; }
    else                   { src = W3; dst = w3m; shift = 11; mode = 2; base = 37888L * 256; }
    long idx = (long)blk * 256 + threadIdx.x - base;
    int row = (int)(idx >> shift);
    int col = (int)(idx & ((1 << shift) - 1));
    float v = src[idx];
    bool keep = true;
    if (mode == 0)      keep = (row % 127) >= col;
    else if (mode == 1) keep = (row % 127) >= (col % 127);
    else if (mode == 2) keep = (row >> 5) > (col % 127);
    dst[idx] = (__bf16)(keep ? v : 0.0f);
}

// ---------------------------------------------------------------------------
// bf16 MFMA GEMM, C[M,N] = A[M,K] * Bw[N,K]^T + bias, optional ReLU.
// 128x128 tile, BK=32, 4 waves (2x2 of 64x64), 16x16x32 MFMA 4x4 per wave.
// global_load_lds width=16 staging, XOR-swizzled LDS 16B slots.
// ---------------------------------------------------------------------------
template <bool RELU, bool OBF16>
__global__ __launch_bounds__(256, 2)
void gemm_bt(const __bf16* __restrict__ A, const __bf16* __restrict__ Bw,
             const float* __restrict__ bias, void* __restrict__ Cout,
             int N, int K)
{
    __shared__ __align__(16) __bf16 lsA[128 * 32];
    __shared__ __align__(16) __bf16 lsB[128 * 32];
    const int tid  = threadIdx.x;
    const int wave = tid >> 6;
    const int lane = tid & 63;
    const int bm = blockIdx.x, bn = blockIdx.y;
    const int wm = wave >> 1, wn = wave & 1;

    const int rsub = lane >> 2;
    const int cbx  = (lane & 3) ^ ((lane >> 3) & 3);
    const __bf16* gsrc[4];
    __bf16* ldst[4];
#pragma unroll
    for (int t = 0; t < 4; ++t) {
        int j = wave * 4 + t;
        if (j < 8) {
            int row = bm * 128 + j * 16 + rsub;
            gsrc[t] = A + (size_t)row * K + cbx * 8;
            ldst[t] = lsA + j * 512;
        } else {
            int jj = j - 8;
            int row = bn * 128 + jj * 16 + rsub;
            gsrc[t] = Bw + (size_t)row * K + cbx * 8;
            ldst[t] = lsB + jj * 512;
        }
    }

    const int fr   = lane & 15;
    const int ks   = lane >> 4;
    const int slot = ks ^ ((fr >> 1) & 3);
    const __bf16* ardp[4];
    const __bf16* brdp[4];
#pragma unroll
    for (int i = 0; i < 4; ++i) {
        ardp[i] = lsA + (wm * 64 + i * 16 + fr) * 32 + slot * 8;
        brdp[i] = lsB + (wn * 64 + i * 16 + fr) * 32 + slot * 8;
    }

    floatx4 acc[4][4];
    const floatx4 vzero = {0.f, 0.f, 0.f, 0.f};
#pragma unroll
    for (int mi = 0; mi < 4; ++mi)
#pragma unroll
        for (int ni = 0; ni < 4; ++ni) acc[mi][ni] = vzero;

    for (int kt = 0; kt < K; kt += 32) {
        __syncthreads();
#pragma unroll
        for (int t = 0; t < 4; ++t) {
            load_lds16((const void*)gsrc[t], (void*)ldst[t]);
            gsrc[t] += 32;
        }
        __syncthreads();
        bf16x8 af[4], bf[4];
#pragma unroll
        for (int i = 0; i < 4; ++i) af[i] = *(const bf16x8*)ardp[i];
#pragma unroll
        for (int i = 0; i < 4; ++i) bf[i] = *(const bf16x8*)brdp[i];
#pragma unroll
        for (int mi = 0; mi < 4; ++mi)
#pragma unroll
            for (int ni = 0; ni < 4; ++ni)
                acc[mi][ni] = __builtin_amdgcn_mfma_f32_16x16x32_bf16(
                    af[mi], bf[ni], acc[mi][ni], 0, 0, 0);
    }

    const int cn  = lane & 15;
    const int cr4 = (lane >> 4) * 4;
#pragma unroll
    for (int ni = 0; ni < 4; ++ni) {
        int col = bn * 128 + wn * 64 + ni * 16 + cn;
        float bv = bias[col];
#pragma unroll
        for (int mi = 0; mi < 4; ++mi) {
            int row0 = bm * 128 + wm * 64 + mi * 16 + cr4;
#pragma unroll
            for (int q = 0; q < 4; ++q) {
                float v = acc[mi][ni][q] + bv;
                if (RELU) v = fmaxf(v, 0.f);
                if (OBF16) ((__bf16*)Cout)[(size_t)(row0 + q) * N + col] = (__bf16)v;
                else       ((float*)Cout)[(size_t)(row0 + q) * N + col] = v;
            }
        }
    }
}

// ---------------------------------------------------------------------------
// Segment-parallel log-semiring chain, ONE THREAD per (batch, segment).
// 126 interior steps = 18 segments x 7. Thread holds the full 4x4 running
// matrix (log2 domain) in registers: no shuffles, no barriers, no LDS.
// Writes P[b][s][16] (row-major r,c).
// ---------------------------------------------------------------------------
__global__ __launch_bounds__(256)
void chain_seg(const float* __restrict__ theta,  // [8192,4096]
               const float* __restrict__ x,      // [8192,128]
               float* __restrict__ P)            // [8192,18,16]
{
    const int b = blockIdx.x * 256 + threadIdx.x;
    const int s = blockIdx.y;                    // 0..17
    const int i0 = 1 + s * 7;
    const float* tp = theta + (size_t)b * 4096 + (size_t)i0 * 32;
    const float* xp = x + (size_t)b * 128 + i0;

    const float LOG2E = 1.4426950408889634f;
    const float C0    = 2.3052328943245633f;     // 0.5*log(2pi) + log(4)

    float M[4][4];
#pragma unroll
    for (int r = 0; r < 4; ++r)
#pragma unroll
        for (int c = 0; c < 4; ++c) M[r][c] = (r == c) ? 0.f : -1e30f;

    for (int ii = 0; ii < 7; ++ii) {
        floatx4 mu[4], al[4];
#pragma unroll
        for (int k = 0; k < 4; ++k) {
            mu[k] = *(const floatx4*)(tp + k * 4);
            al[k] = *(const floatx4*)(tp + 16 + k * 4);
        }
        float xv = xp[ii];
        tp += 32;
        float lp[4][4];
#pragma unroll
        for (int k = 0; k < 4; ++k)
#pragma unroll
            for (int c = 0; c < 4; ++c) {
                float a = al[k][c];
                float e = fexp2(-a * LOG2E);
                float z = (xv - mu[k][c]) * e;
                lp[k][c] = (-0.5f * z * z - a - C0) * LOG2E;
            }
        float Mn[4][4];
#pragma unroll
        for (int r = 0; r < 4; ++r)
#pragma unroll
            for (int c = 0; c < 4; ++c) {
                float a0 = M[r][0] + lp[0][c];
                float a1 = M[r][1] + lp[1][c];
                float a2 = M[r][2] + lp[2][c];
                float a3 = M[r][3] + lp[3][c];
                float mx = fmaxf(fmaxf(a0, a1), fmaxf(a2, a3));
                float sm = fexp2(a0 - mx) + fexp2(a1 - mx) +
                           fexp2(a2 - mx) + fexp2(a3 - mx);
                Mn[r][c] = mx + flog2(sm);
            }
#pragma unroll
        for (int r = 0; r < 4; ++r)
#pragma unroll
            for (int c = 0; c < 4; ++c) M[r][c] = Mn[r][c];
    }

    float* pb = P + ((size_t)b * 18 + s) * 16;
#pragma unroll
    for (int r = 0; r < 4; ++r) {
        floatx4 o = {M[r][0], M[r][1], M[r][2], M[r][3]};
        *(floatx4*)(pb + r * 4) = o;
    }
}

// ---------------------------------------------------------------------------
// Combine: fold 18 segment matrices + first/last boundary vectors per batch.
// 4 lanes per batch (lane r = row r), shuffles for the row exchange.
// ---------------------------------------------------------------------------
__global__ __launch_bounds__(256)
void chain_fin(const float* __restrict__ theta,  // [8192,4096]
               const float* __restrict__ x,      // [8192,128]
               const float* __restrict__ P,      // [8192,18,16]
               float* __restrict__ out)          // [8192]
{
    const int tid  = threadIdx.x;
    const int lane = tid & 63;
    const int r    = lane & 3;
    const int l0   = lane & 60;
    const int b    = blockIdx.x * 64 + (tid >> 2);
    const size_t tbase = (size_t)b * 4096;

    const float LOG2E = 1.4426950408889634f;
    const float LN2   = 0.6931471805599453f;
    const float C0    = 2.3052328943245633f;

    const float* Pb = P + (size_t)b * 288;       // 18*16
    floatx4 m0 = *(const floatx4*)(Pb + r * 4);
    float M[4] = {m0[0], m0[1], m0[2], m0[3]};

#pragma unroll
    for (int s = 1; s < 18; ++s) {
        floatx4 lr = *(const floatx4*)(Pb + s * 16 + r * 4);
        float Mn[4];
#pragma unroll
        for (int c = 0; c < 4; ++c) {
            float a0 = M[0] + __shfl(lr[c], l0 + 0);
            float a1 = M[1] + __shfl(lr[c], l0 + 1);
            float a2 = M[2] + __shfl(lr[c], l0 + 2);
            float a3 = M[3] + __shfl(lr[c], l0 + 3);
            float mx = fmaxf(fmaxf(a0, a1), fmaxf(a2, a3));
            float sm = fexp2(a0 - mx) + fexp2(a1 - mx) + fexp2(a2 - mx) + fexp2(a3 - mx);
            Mn[c] = mx + flog2(sm);
        }
#pragma unroll
        for (int k = 0; k < 4; ++k) M[k] = Mn[k];
    }

    // t[r] = lse_c(M[r][c] + last[c]),  last[c] = logp[b,127,c,0]
    float xl = x[(size_t)b * 128 + 127];
    float a[4];
#pragma unroll
    for (int c = 0; c < 4; ++c) {
        float mu_ = theta[tbase + 4064 + c * 4];
        float al_ = theta[tbase + 4064 + 16 + c * 4];
        float e = fexp2(-al_ * LOG2E);
        float z = (xl - mu_) * e;
        float lp2 = (-0.5f * z * z - al_ - C0) * LOG2E;
        a[c] = M[c] + lp2;
    }
    float mx = fmaxf(fmaxf(a[0], a[1]), fmaxf(a[2], a[3]));
    float tr = mx + flog2(fexp2(a[0] - mx) + fexp2(a[1] - mx) +
                          fexp2(a[2] - mx) + fexp2(a[3] - mx));

    // out = lse_r(first[r] + t[r]),  first[r] = logp[b,0,0,r]
    float x0  = x[(size_t)b * 128];
    float muf = theta[tbase + r];
    float alf = theta[tbase + 16 + r];
    float ef = fexp2(-alf * LOG2E);
    float zf = (x0 - muf) * ef;
    float f2 = (-0.5f * zf * zf - alf - C0) * LOG2E;
    float v = f2 + tr;
    float m1 = fmaxf(v, __shfl_xor(v, 1));
    float m2 = fmaxf(m1, __shfl_xor(m1, 2));
    float sum = fexp2(v - m2);
    sum += __shfl_xor(sum, 1);
    sum += __shfl_xor(sum, 2);
    if (r == 0) out[b] = (m2 + flog2(sum)) * LN2;
}

// ---------------------------------------------------------------------------
extern "C" void kernel_launch(void* const* d_in, const int* in_sizes, int n_in,
                              void* d_out, int out_size, void* d_ws, size_t ws_size,
                              hipStream_t stream)
{
    (void)in_sizes; (void)n_in; (void)out_size; (void)ws_size;
    const float* x  = (const float*)d_in[0];
    const float* W0 = (const float*)d_in[1];
    const float* b0 = (const float*)d_in[2];
    const float* W1 = (const float*)d_in[3];
    const float* b1 = (const float*)d_in[4];
    const float* W2 = (const float*)d_in[5];
    const float* b2 = (const float*)d_in[6];
    const float* W3 = (const float*)d_in[7];
    const float* b3 = (const float*)d_in[8];

    char* ws = (char*)d_ws;
    size_t off = 0;
    auto alloc = [&](size_t bytes) { char* p = ws + off; off += bytes; return p; };
    __bf16* xb  = (__bf16*)alloc((size_t)8192 * 128 * 2);    // 2 MB
    __bf16* w0m = (__bf16*)alloc((size_t)2048 * 128 * 2);    // 0.5 MB
    __bf16* w1m = (__bf16*)alloc((size_t)2048 * 2048 * 2);   // 8 MB
    __bf16* w2m = (__bf16*)alloc((size_t)2048 * 2048 * 2);   // 8 MB
    __bf16* w3m = (__bf16*)alloc((size_t)4096 * 2048 * 2);   // 16 MB
    __bf16* h1  = (__bf16*)alloc((size_t)8192 * 2048 * 2);   // 32 MB
    __bf16* h2  = (__bf16*)alloc((size_t)8192 * 2048 * 2);   // 32 MB
    float*  th  = (float*) alloc((size_t)8192 * 4096 * 4);   // 128 MB
    __bf16* h3  = h1;            // h1 dead after GEMM2; reuse for h3
    float*  P   = (float*)h2;    // h2 dead after GEMM3; P = 9.4 MB << 32 MB

    // fused masked-weight + x prep (single launch)
    prep_all<<<70656, 256, 0, stream>>>(x, W0, W1, W2, W3, xb, w0m, w1m, w2m, w3m);

    // 4 GEMMs: C[8192,N] = A * W^T + b
    gemm_bt<true,  true ><<<dim3(64, 16), 256, 0, stream>>>(xb, w0m, b0, h1, 2048, 128);
    gemm_bt<true,  true ><<<dim3(64, 16), 256, 0, stream>>>(h1, w1m, b1, h2, 2048, 2048);
    gemm_bt<true,  true ><<<dim3(64, 16), 256, 0, stream>>>(h2, w2m, b2, h3, 2048, 2048);
    gemm_bt<false, false><<<dim3(64, 32), 256, 0, stream>>>(h3, w3m, b3, th, 4096, 2048);

    // segment-parallel log-semiring chain (scalar per-thread matrices)
    chain_seg<<<dim3(32, 18), 256, 0, stream>>>(th, x, P);
    chain_fin<<<128, 256, 0, stream>>>(th, x, P, (float*)d_out);
}

// Round 4
// 480.896 us; speedup vs baseline: 1.0091x; 1.0091x over previous
//
#include <hip/hip_runtime.h>
#include <hip/hip_bf16.h>
#include <cstdint>
#include <cstddef>

#define AS1 __attribute__((address_space(1)))
#define AS3 __attribute__((address_space(3)))

typedef __bf16 bf16x8 __attribute__((ext_vector_type(8)));
typedef float  floatx4 __attribute__((ext_vector_type(4)));

__device__ __forceinline__ void load_lds16(const void* g, void* l) {
    __builtin_amdgcn_global_load_lds((AS1 void*)g, (AS3 void*)l, 16, 0, 0);
}

__device__ __forceinline__ float fexp2(float x) { return __builtin_amdgcn_exp2f(x); }
__device__ __forceinline__ float flog2(float x) { return __builtin_amdgcn_logf(x); }

// ---------------------------------------------------------------------------
// Fused prep: all masks + fp32->bf16 in ONE launch.
// ---------------------------------------------------------------------------
__global__ __launch_bounds__(256)
void prep_all(const float* __restrict__ x,  const float* __restrict__ W0,
              const float* __restrict__ W1, const float* __restrict__ W2,
              const float* __restrict__ W3,
              __bf16* __restrict__ xb,  __bf16* __restrict__ w0m,
              __bf16* __restrict__ w1m, __bf16* __restrict__ w2m,
              __bf16* __restrict__ w3m)
{
    const int blk = blockIdx.x;
    const float* src; __bf16* dst; int shift, mode; long base;
    if (blk < 4096)        { src = x;  dst = xb;  shift = 7;  mode = 3; base = 0; }
    else if (blk < 5120)   { src = W0; dst = w0m; shift = 7;  mode = 0; base = 4096L * 256; }
    else if (blk < 21504)  { src = W1; dst = w1m; shift = 11; mode = 1; base = 5120L * 256; }
    else if (blk < 37888)  { src = W2; dst = w2m; shift = 11; mode = 1; base = 21504L * 256; }
    else                   { src = W3; dst = w3m; shift = 11; mode = 2; base = 37888L * 256; }
    long idx = (long)blk * 256 + threadIdx.x - base;
    int row = (int)(idx >> shift);
    int col = (int)(idx & ((1 << shift) - 1));
    float v = src[idx];
    bool keep = true;
    if (mode == 0)      keep = (row % 127) >= col;
    else if (mode == 1) keep = (row % 127) >= (col % 127);
    else if (mode == 2) keep = (row >> 5) > (col % 127);
    dst[idx] = (__bf16)(keep ? v : 0.0f);
}

// ---------------------------------------------------------------------------
// bf16 MFMA GEMM, C[M,N] = A[M,K] * Bw[N,K]^T + bias, optional ReLU.
// TLAYOUT: store fp32 into batch-interleaved th2[b>>6][col][b&63]
//          (addr = (b>>6)*N*64 + col*64 + (b&63)) for coalesced chain reads.
// ---------------------------------------------------------------------------
template <bool RELU, bool OBF16, bool TLAYOUT>
__global__ __launch_bounds__(256, 2)
void gemm_bt(const __bf16* __restrict__ A, const __bf16* __restrict__ Bw,
             const float* __restrict__ bias, void* __restrict__ Cout,
             int N, int K)
{
    __shared__ __align__(16) __bf16 lsA[128 * 32];
    __shared__ __align__(16) __bf16 lsB[128 * 32];
    const int tid  = threadIdx.x;
    const int wave = tid >> 6;
    const int lane = tid & 63;
    const int bm = blockIdx.x, bn = blockIdx.y;
    const int wm = wave >> 1, wn = wave & 1;

    const int rsub = lane >> 2;
    const int cbx  = (lane & 3) ^ ((lane >> 3) & 3);
    const __bf16* gsrc[4];
    __bf16* ldst[4];
#pragma unroll
    for (int t = 0; t < 4; ++t) {
        int j = wave * 4 + t;
        if (j < 8) {
            int row = bm * 128 + j * 16 + rsub;
            gsrc[t] = A + (size_t)row * K + cbx * 8;
            ldst[t] = lsA + j * 512;
        } else {
            int jj = j - 8;
            int row = bn * 128 + jj * 16 + rsub;
            gsrc[t] = Bw + (size_t)row * K + cbx * 8;
            ldst[t] = lsB + jj * 512;
        }
    }

    const int fr   = lane & 15;
    const int ks   = lane >> 4;
    const int slot = ks ^ ((fr >> 1) & 3);
    const __bf16* ardp[4];
    const __bf16* brdp[4];
#pragma unroll
    for (int i = 0; i < 4; ++i) {
        ardp[i] = lsA + (wm * 64 + i * 16 + fr) * 32 + slot * 8;
        brdp[i] = lsB + (wn * 64 + i * 16 + fr) * 32 + slot * 8;
    }

    floatx4 acc[4][4];
    const floatx4 vzero = {0.f, 0.f, 0.f, 0.f};
#pragma unroll
    for (int mi = 0; mi < 4; ++mi)
#pragma unroll
        for (int ni = 0; ni < 4; ++ni) acc[mi][ni] = vzero;

    for (int kt = 0; kt < K; kt += 32) {
        __syncthreads();
#pragma unroll
        for (int t = 0; t < 4; ++t) {
            load_lds16((const void*)gsrc[t], (void*)ldst[t]);
            gsrc[t] += 32;
        }
        __syncthreads();
        bf16x8 af[4], bf[4];
#pragma unroll
        for (int i = 0; i < 4; ++i) af[i] = *(const bf16x8*)ardp[i];
#pragma unroll
        for (int i = 0; i < 4; ++i) bf[i] = *(const bf16x8*)brdp[i];
#pragma unroll
        for (int mi = 0; mi < 4; ++mi)
#pragma unroll
            for (int ni = 0; ni < 4; ++ni)
                acc[mi][ni] = __builtin_amdgcn_mfma_f32_16x16x32_bf16(
                    af[mi], bf[ni], acc[mi][ni], 0, 0, 0);
    }

    const int cn  = lane & 15;
    const int cr4 = (lane >> 4) * 4;
#pragma unroll
    for (int ni = 0; ni < 4; ++ni) {
        int col = bn * 128 + wn * 64 + ni * 16 + cn;
        float bv = bias[col];
#pragma unroll
        for (int mi = 0; mi < 4; ++mi) {
            int row0 = bm * 128 + wm * 64 + mi * 16 + cr4;
#pragma unroll
            for (int q = 0; q < 4; ++q) {
                float v = acc[mi][ni][q] + bv;
                if (RELU) v = fmaxf(v, 0.f);
                if (TLAYOUT) {
                    // b = row0+q; b>>6 = bm*2+wm; b&63 = mi*16+cr4+q
                    size_t addr = (size_t)(bm * 2 + wm) * ((size_t)N * 64)
                                + (size_t)col * 64 + (mi * 16 + cr4 + q);
                    ((float*)Cout)[addr] = v;
                } else if (OBF16) {
                    ((__bf16*)Cout)[(size_t)(row0 + q) * N + col] = (__bf16)v;
                } else {
                    ((float*)Cout)[(size_t)(row0 + q) * N + col] = v;
                }
            }
        }
    }
}

// ---------------------------------------------------------------------------
// Segment-parallel log-semiring chain, one thread per (batch, segment).
// theta in batch-interleaved layout th2[b>>6][f][b&63]: a wave covers 64
// consecutive batches, so every per-step load (element f, all lanes) is one
// contiguous 256B segment. No LDS, no shuffles, no barriers.
// ---------------------------------------------------------------------------
__global__ __launch_bounds__(256)
void chain_seg(const float* __restrict__ th2,   // [128][4096][64]
               const float* __restrict__ x,     // [8192,128]
               float* __restrict__ P)           // [8192,18,16]
{
    const int b = blockIdx.x * 256 + threadIdx.x;
    const int s = blockIdx.y;                    // 0..17
    const int i0 = 1 + s * 7;
    const float* tp = th2 + (size_t)(b >> 6) * (4096 * 64) + (b & 63)
                          + (size_t)i0 * 32 * 64;
    const float* xp = x + (size_t)b * 128 + i0;

    const float LOG2E = 1.4426950408889634f;
    const float C0    = 2.3052328943245633f;     // 0.5*log(2pi) + log(4)

    float M[4][4];
#pragma unroll
    for (int r = 0; r < 4; ++r)
#pragma unroll
        for (int c = 0; c < 4; ++c) M[r][c] = (r == c) ? 0.f : -1e30f;

    for (int ii = 0; ii < 7; ++ii) {
        float mu[16], al[16];
#pragma unroll
        for (int j = 0; j < 16; ++j) mu[j] = tp[(size_t)j * 64];
#pragma unroll
        for (int j = 0; j < 16; ++j) al[j] = tp[(size_t)(16 + j) * 64];
        float xv = xp[ii];
        tp += 32 * 64;
        float lp[16];
#pragma unroll
        for (int j = 0; j < 16; ++j) {
            float a = al[j];
            float e = fexp2(-a * LOG2E);
            float z = (xv - mu[j]) * e;
            lp[j] = (-0.5f * z * z - a - C0) * LOG2E;
        }
        float Mn[4][4];
#pragma unroll
        for (int r = 0; r < 4; ++r)
#pragma unroll
            for (int c = 0; c < 4; ++c) {
                float a0 = M[r][0] + lp[0 * 4 + c];
                float a1 = M[r][1] + lp[1 * 4 + c];
                float a2 = M[r][2] + lp[2 * 4 + c];
                float a3 = M[r][3] + lp[3 * 4 + c];
                float mx = fmaxf(fmaxf(a0, a1), fmaxf(a2, a3));
                float sm = fexp2(a0 - mx) + fexp2(a1 - mx) +
                           fexp2(a2 - mx) + fexp2(a3 - mx);
                Mn[r][c] = mx + flog2(sm);
            }
#pragma unroll
        for (int r = 0; r < 4; ++r)
#pragma unroll
            for (int c = 0; c < 4; ++c) M[r][c] = Mn[r][c];
    }

    float* pb = P + ((size_t)b * 18 + s) * 16;
#pragma unroll
    for (int r = 0; r < 4; ++r) {
        floatx4 o = {M[r][0], M[r][1], M[r][2], M[r][3]};
        *(floatx4*)(pb + r * 4) = o;
    }
}

// ---------------------------------------------------------------------------
// Combine: fold 18 segment matrices + first/last boundary vectors per batch.
// 4 lanes per batch (lane r = row r), shuffles for the row exchange.
// ---------------------------------------------------------------------------
__global__ __launch_bounds__(256)
void chain_fin(const float* __restrict__ th2,   // [128][4096][64]
               const float* __restrict__ x,     // [8192,128]
               const float* __restrict__ P,     // [8192,18,16]
               float* __restrict__ out)         // [8192]
{
    const int tid  = threadIdx.x;
    const int lane = tid & 63;
    const int r    = lane & 3;
    const int l0   = lane & 60;
    const int b    = blockIdx.x * 64 + (tid >> 2);
    const float* tb = th2 + (size_t)(b >> 6) * (4096 * 64) + (b & 63);

    const float LOG2E = 1.4426950408889634f;
    const float LN2   = 0.6931471805599453f;
    const float C0    = 2.3052328943245633f;

    const float* Pb = P + (size_t)b * 288;       // 18*16
    floatx4 m0 = *(const floatx4*)(Pb + r * 4);
    float M[4] = {m0[0], m0[1], m0[2], m0[3]};

#pragma unroll
    for (int s = 1; s < 18; ++s) {
        floatx4 lr = *(const floatx4*)(Pb + s * 16 + r * 4);
        float Mn[4];
#pragma unroll
        for (int c = 0; c < 4; ++c) {
            float a0 = M[0] + __shfl(lr[c], l0 + 0);
            float a1 = M[1] + __shfl(lr[c], l0 + 1);
            float a2 = M[2] + __shfl(lr[c], l0 + 2);
            float a3 = M[3] + __shfl(lr[c], l0 + 3);
            float mx = fmaxf(fmaxf(a0, a1), fmaxf(a2, a3));
            float sm = fexp2(a0 - mx) + fexp2(a1 - mx) + fexp2(a2 - mx) + fexp2(a3 - mx);
            Mn[c] = mx + flog2(sm);
        }
#pragma unroll
        for (int k = 0; k < 4; ++k) M[k] = Mn[k];
    }

    // t[r] = lse_c(M[r][c] + last[c]),  last[c] = logp[b,127,c,0]
    float xl = x[(size_t)b * 128 + 127];
    float a[4];
#pragma unroll
    for (int c = 0; c < 4; ++c) {
        float mu_ = tb[(size_t)(4064 + c * 4) * 64];
        float al_ = tb[(size_t)(4064 + 16 + c * 4) * 64];
        float e = fexp2(-al_ * LOG2E);
        float z = (xl - mu_) * e;
        float lp2 = (-0.5f * z * z - al_ - C0) * LOG2E;
        a[c] = M[c] + lp2;
    }
    float mx = fmaxf(fmaxf(a[0], a[1]), fmaxf(a[2], a[3]));
    float tr = mx + flog2(fexp2(a[0] - mx) + fexp2(a[1] - mx) +
                          fexp2(a[2] - mx) + fexp2(a[3] - mx));

    // out = lse_r(first[r] + t[r]),  first[r] = logp[b,0,0,r]
    float x0  = x[(size_t)b * 128];
    float muf = tb[(size_t)r * 64];
    float alf = tb[(size_t)(16 + r) * 64];
    float ef = fexp2(-alf * LOG2E);
    float zf = (x0 - muf) * ef;
    float f2 = (-0.5f * zf * zf - alf - C0) * LOG2E;
    float v = f2 + tr;
    float m1 = fmaxf(v, __shfl_xor(v, 1));
    float m2 = fmaxf(m1, __shfl_xor(m1, 2));
    float sum = fexp2(v - m2);
    sum += __shfl_xor(sum, 1);
    sum += __shfl_xor(sum, 2);
    if (r == 0) out[b] = (m2 + flog2(sum)) * LN2;
}

// ---------------------------------------------------------------------------
extern "C" void kernel_launch(void* const* d_in, const int* in_sizes, int n_in,
                              void* d_out, int out_size, void* d_ws, size_t ws_size,
                              hipStream_t stream)
{
    (void)in_sizes; (void)n_in; (void)out_size; (void)ws_size;
    const float* x  = (const float*)d_in[0];
    const float* W0 = (const float*)d_in[1];
    const float* b0 = (const float*)d_in[2];
    const float* W1 = (const float*)d_in[3];
    const float* b1 = (const float*)d_in[4];
    const float* W2 = (const float*)d_in[5];
    const float* b2 = (const float*)d_in[6];
    const float* W3 = (const float*)d_in[7];
    const float* b3 = (const float*)d_in[8];

    char* ws = (char*)d_ws;
    size_t off = 0;
    auto alloc = [&](size_t bytes) { char* p = ws + off; off += bytes; return p; };
    __bf16* xb  = (__bf16*)alloc((size_t)8192 * 128 * 2);    // 2 MB
    __bf16* w0m = (__bf16*)alloc((size_t)2048 * 128 * 2);    // 0.5 MB
    __bf16* w1m = (__bf16*)alloc((size_t)2048 * 2048 * 2);   // 8 MB
    __bf16* w2m = (__bf16*)alloc((size_t)2048 * 2048 * 2);   // 8 MB
    __bf16* w3m = (__bf16*)alloc((size_t)4096 * 2048 * 2);   // 16 MB
    __bf16* h1  = (__bf16*)alloc((size_t)8192 * 2048 * 2);   // 32 MB
    __bf16* h2  = (__bf16*)alloc((size_t)8192 * 2048 * 2);   // 32 MB
    float*  th  = (float*) alloc((size_t)8192 * 4096 * 4);   // 128 MB (batch-interleaved)
    __bf16* h3  = h1;            // h1 dead after GEMM2; reuse for h3
    float*  P   = (float*)h2;    // h2 dead after GEMM3; P = 9.4 MB << 32 MB

    // fused masked-weight + x prep (single launch)
    prep_all<<<70656, 256, 0, stream>>>(x, W0, W1, W2, W3, xb, w0m, w1m, w2m, w3m);

    // 4 GEMMs: C[8192,N] = A * W^T + b
    gemm_bt<true,  true,  false><<<dim3(64, 16), 256, 0, stream>>>(xb, w0m, b0, h1, 2048, 128);
    gemm_bt<true,  true,  false><<<dim3(64, 16), 256, 0, stream>>>(h1, w1m, b1, h2, 2048, 2048);
    gemm_bt<true,  true,  false><<<dim3(64, 16), 256, 0, stream>>>(h2, w2m, b2, h3, 2048, 2048);
    gemm_bt<false, false, true ><<<dim3(64, 32), 256, 0, stream>>>(h3, w3m, b3, th, 4096, 2048);

    // segment-parallel log-semiring chain (coalesced batch-interleaved reads)
    chain_seg<<<dim3(32, 18), 256, 0, stream>>>(th, x, P);
    chain_fin<<<128, 256, 0, stream>>>(th, x, P, (float*)d_out);
}